// Round 2
// baseline (6117.040 us; speedup 1.0000x reference)
//
#include <hip/hip_runtime.h>
#include <math.h>

// Problem constants
#define V_  8185
#define E_  353
#define H_  191
#define FH_ 764
#define Z_  13
#define T_  25
#define START_ 19
#define VP_ 8192
#define NB_ 512     // persistent grid: 512 blocks = 2 blocks/CU on 256 CUs

__device__ __forceinline__ float sigf(float x) { return 1.0f / (1.0f + expf(-x)); }

// Shared-memory union across phases (max member 22.6 KB -> 2 blocks/CU fits)
union SMem {
  float AT_g[16 * E_];          // prologue GEMM A-tile (transposed)
  struct {
    float hs[16 * H_];
    float xs[16 * 32];
    float bs[32];
    float gb[32 * 16];
    int   tk[16];
  } l;                          // lstm phase
  float AT_l[16 * H_];          // logits phase A-tile
  float zs[16 * Z_];            // latent phase
};

// ---------------------------------------------------------------------------
// Sense-reversal barrier. bar[0]=cnt, bar[1]=gen, one 128B line per domain.
// Arrive: release; depart: acquire -> all pre-barrier writes of members are
// visible to all members (agent scope handles cross-XCD).
// ---------------------------------------------------------------------------
__device__ __forceinline__ void bar_sync(unsigned* bar, unsigned members) {
  __syncthreads();
  if (threadIdx.x == 0) {
    unsigned g = __hip_atomic_load(bar + 1, __ATOMIC_RELAXED, __HIP_MEMORY_SCOPE_AGENT);
    unsigned a = __hip_atomic_fetch_add(bar, 1u, __ATOMIC_ACQ_REL, __HIP_MEMORY_SCOPE_AGENT);
    if (a == members - 1) {
      __hip_atomic_store(bar, 0u, __ATOMIC_RELAXED, __HIP_MEMORY_SCOPE_AGENT);
      __hip_atomic_fetch_add(bar + 1, 1u, __ATOMIC_RELEASE, __HIP_MEMORY_SCOPE_AGENT);
    } else {
      while (__hip_atomic_load(bar + 1, __ATOMIC_ACQUIRE, __HIP_MEMORY_SCOPE_AGENT) == g)
        __builtin_amdgcn_s_sleep(4);
    }
  }
  __syncthreads();
}

// Orderable packing for exact argmax (max value, ties -> smallest index).
__device__ __forceinline__ unsigned long long pack_key(float v, int idx) {
  unsigned u = __float_as_uint(v);
  u = (u & 0x80000000u) ? ~u : (u | 0x80000000u);
  return ((unsigned long long)u << 32) | (unsigned)(0x7FFFFFFFu - idx);
}

// ---------------------------------------------------------------------------
// One 16x256 tile of C[M][764] = A[M][353] @ W[353][764].
// mode 0: A row m = emb[m]; mode 1: A row m=(t*B+b) = emb[inputs[b*T+t]].
// ---------------------------------------------------------------------------
__device__ void gemm_tile(const float* __restrict__ emb, const float* __restrict__ W,
                          float* __restrict__ C, int M, int ct, int m0,
                          const int* __restrict__ inputs, int mode, int B,
                          float* AT) {
  const int tid = threadIdx.x;
  const int n0 = ct * 256;
  __syncthreads();   // previous AT users done
  for (int i = tid; i < 16 * E_; i += 256) {
    int r = i / E_, k = i - r * E_;
    int m = m0 + r;
    float v = 0.0f;
    if (m < M) {
      int row;
      if (mode == 0) row = m;
      else { int t = m / B, bb = m - t * B; row = inputs[bb * T_ + t]; }
      v = emb[(size_t)row * E_ + k];
    }
    AT[k * 16 + r] = v;
  }
  __syncthreads();
  const int lane = tid & 63;
  const int w4 = (tid >> 6) * 4;
  const int j = n0 + lane * 4;
  if (j < FH_) {
    float4 c0 = {0,0,0,0}, c1 = {0,0,0,0}, c2 = {0,0,0,0}, c3 = {0,0,0,0};
    const float* wc = W + j;
    const float* at = AT + w4;
    for (int k = 0; k < E_; ++k) {
      float4 wv = *(const float4*)(wc + (size_t)k * FH_);
      float4 a  = *(const float4*)(at + k * 16);
      c0.x = fmaf(a.x, wv.x, c0.x); c0.y = fmaf(a.x, wv.y, c0.y);
      c0.z = fmaf(a.x, wv.z, c0.z); c0.w = fmaf(a.x, wv.w, c0.w);
      c1.x = fmaf(a.y, wv.x, c1.x); c1.y = fmaf(a.y, wv.y, c1.y);
      c1.z = fmaf(a.y, wv.z, c1.z); c1.w = fmaf(a.y, wv.w, c1.w);
      c2.x = fmaf(a.z, wv.x, c2.x); c2.y = fmaf(a.z, wv.y, c2.y);
      c2.z = fmaf(a.z, wv.z, c2.z); c2.w = fmaf(a.z, wv.w, c2.w);
      c3.x = fmaf(a.w, wv.x, c3.x); c3.y = fmaf(a.w, wv.y, c3.y);
      c3.z = fmaf(a.w, wv.z, c3.z); c3.w = fmaf(a.w, wv.w, c3.w);
    }
    const int mb = m0 + w4;
    if (mb + 0 < M) *(float4*)(C + (size_t)(mb + 0) * FH_ + j) = c0;
    if (mb + 1 < M) *(float4*)(C + (size_t)(mb + 1) * FH_ + j) = c1;
    if (mb + 2 < M) *(float4*)(C + (size_t)(mb + 2) * FH_ + j) = c2;
    if (mb + 3 < M) *(float4*)(C + (size_t)(mb + 3) * FH_ + j) = c3;
  }
}

// ---------------------------------------------------------------------------
// One LSTM step for 16 batch rows (m0..m0+15) x 8 h-cols (cb*8..+7).
// MODE 0 encoder: xrow = xk + (m0+row)*764
// MODE 1 decoder: xrow = EK + token[row]*764; token from tok_prev keys
//                 (nullptr -> START).
// ---------------------------------------------------------------------------
template <int MODE>
__device__ void lstm_dev(const float* __restrict__ xk, const float* __restrict__ rk,
                         const float* __restrict__ bias,
                         const float* __restrict__ h_in, const float* __restrict__ c_in,
                         float* __restrict__ h_out, float* __restrict__ c_out,
                         const unsigned long long* __restrict__ tok_prev,
                         int cb, int m0, SMem& sm) {
  const int tid = threadIdx.x;
  const int c0 = cb * 8;

  if (MODE) {
    if (tid < 16) {
      int tkn = START_;
      if (tok_prev) {
        unsigned long long key = tok_prev[m0 + tid];
        tkn = (int)(0x7FFFFFFFu - (unsigned)(key & 0xFFFFFFFFu));
      }
      sm.l.tk[tid] = tkn;
    }
    __syncthreads();
  }

  for (int i = tid; i < 16 * H_; i += 256) sm.l.hs[i] = h_in[(size_t)m0 * H_ + i];
  for (int i = tid; i < 16 * 32; i += 256) {
    int row = i >> 5, q = i & 31;
    int jj = c0 + (q & 7);
    int jg = jj + H_ * (q >> 3);
    float xv = 0.0f;
    if (jj < H_) {
      const float* xrow = MODE ? (xk + (size_t)sm.l.tk[row] * FH_)
                               : (xk + (size_t)(m0 + row) * FH_);
      xv = xrow[jg];
    }
    sm.l.xs[i] = xv;
  }
  if (tid < 32) {
    int jj = c0 + (tid & 7);
    sm.l.bs[tid] = (jj < H_) ? bias[jj + H_ * (tid >> 3)] : 0.0f;
  }
  __syncthreads();

  const int q = tid & 31, rgi = tid >> 5;
  const int jj = c0 + (q & 7);
  const int jg = jj + H_ * (q >> 3);
  float a0 = 0.0f, a1 = 0.0f;
  if (jj < H_) {
    const float* rkp = rk + jg;
    const float* h0p = sm.l.hs + rgi * H_;
    const float* h1p = sm.l.hs + (rgi + 8) * H_;
    for (int k = 0; k < H_; ++k) {
      float wv = rkp[(size_t)k * FH_];
      a0 = fmaf(h0p[k], wv, a0);
      a1 = fmaf(h1p[k], wv, a1);
    }
  }
  sm.l.gb[q * 16 + rgi] = a0;
  sm.l.gb[q * 16 + rgi + 8] = a1;
  __syncthreads();

  if (tid < 128) {
    int cc = tid & 7, row = tid >> 3;
    int jc = c0 + cc;
    if (jc < H_) {
      float gi = sm.l.gb[(cc     ) * 16 + row] + sm.l.xs[row * 32 + cc     ] + sm.l.bs[cc];
      float gf = sm.l.gb[( 8 + cc) * 16 + row] + sm.l.xs[row * 32 +  8 + cc] + sm.l.bs[ 8 + cc];
      float gg = sm.l.gb[(16 + cc) * 16 + row] + sm.l.xs[row * 32 + 16 + cc] + sm.l.bs[16 + cc];
      float go = sm.l.gb[(24 + cc) * 16 + row] + sm.l.xs[row * 32 + 24 + cc] + sm.l.bs[24 + cc];
      float co = c_in[(size_t)(m0 + row) * H_ + jc];
      float cn = sigf(gf) * co + sigf(gi) * tanhf(gg);
      float hn = sigf(go) * tanhf(cn);
      c_out[(size_t)(m0 + row) * H_ + jc] = cn;
      h_out[(size_t)(m0 + row) * H_ + jc] = hn;
    }
  }
}

// ---------------------------------------------------------------------------
// logits tile: 16 rows x 256 cols of h @ WP + out_b; store to out[:,t,:];
// atomicMax packed argmax key into tok_cur[row].
// ---------------------------------------------------------------------------
__device__ void logits_dev(const float* __restrict__ h, const float* __restrict__ wp,
                           const float* __restrict__ ob, float* __restrict__ out,
                           int t, unsigned long long* __restrict__ tok_cur,
                           int ct, int m0, float* AT) {
  const int tid = threadIdx.x;
  const int n0 = ct * 256;
  for (int i = tid; i < 16 * H_; i += 256) {
    int r = i / H_, k = i - r * H_;
    AT[k * 16 + r] = h[(size_t)m0 * H_ + i];
  }
  __syncthreads();
  const int lane = tid & 63;
  const int w4 = (tid >> 6) * 4;
  const int j = n0 + lane * 4;
  float4 c0 = {0,0,0,0}, c1 = {0,0,0,0}, c2 = {0,0,0,0}, c3 = {0,0,0,0};
  const float* wc = wp + j;
  const float* at = AT + w4;
  for (int k = 0; k < H_; ++k) {
    float4 wv = *(const float4*)(wc + (size_t)k * VP_);
    float4 a  = *(const float4*)(at + k * 16);
    c0.x = fmaf(a.x, wv.x, c0.x); c0.y = fmaf(a.x, wv.y, c0.y);
    c0.z = fmaf(a.x, wv.z, c0.z); c0.w = fmaf(a.x, wv.w, c0.w);
    c1.x = fmaf(a.y, wv.x, c1.x); c1.y = fmaf(a.y, wv.y, c1.y);
    c1.z = fmaf(a.y, wv.z, c1.z); c1.w = fmaf(a.y, wv.w, c1.w);
    c2.x = fmaf(a.z, wv.x, c2.x); c2.y = fmaf(a.z, wv.y, c2.y);
    c2.z = fmaf(a.z, wv.z, c2.z); c2.w = fmaf(a.z, wv.w, c2.w);
    c3.x = fmaf(a.w, wv.x, c3.x); c3.y = fmaf(a.w, wv.y, c3.y);
    c3.z = fmaf(a.w, wv.z, c3.z); c3.w = fmaf(a.w, wv.w, c3.w);
  }
  float bias[4];
#pragma unroll
  for (int u = 0; u < 4; ++u) bias[u] = (j + u < V_) ? ob[j + u] : 0.0f;
  float4 accs[4] = {c0, c1, c2, c3};
  const int b0 = m0 + w4;
#pragma unroll
  for (int r = 0; r < 4; ++r) {
    const int b = b0 + r;
    float v[4] = {accs[r].x + bias[0], accs[r].y + bias[1],
                  accs[r].z + bias[2], accs[r].w + bias[3]};
    float* orow = out + ((size_t)b * T_ + t) * V_ + j;
#pragma unroll
    for (int u = 0; u < 4; ++u)
      if (j + u < V_) orow[u] = v[u];
    float bv = -INFINITY; int bi = 0;
#pragma unroll
    for (int u = 0; u < 4; ++u)
      if (j + u < V_ && v[u] > bv) { bv = v[u]; bi = j + u; }
#pragma unroll
    for (int off = 1; off < 64; off <<= 1) {
      float ov = __shfl_xor(bv, off, 64);
      int   oi = __shfl_xor(bi, off, 64);
      if (ov > bv || (ov == bv && oi < bi)) { bv = ov; bi = oi; }
    }
    if (lane == 0) atomicMax(tok_cur + b, pack_key(bv, bi));
  }
}

// ---------------------------------------------------------------------------
// latent for 16 rows: z = (h@mu_w+mu_b) + eps*(h@sig_w+sig_b);
// h0 = c0 = z@init_w + init_b.
// ---------------------------------------------------------------------------
__device__ void latent_dev(const float* __restrict__ h, const float* __restrict__ eps,
                           const float* __restrict__ mu_w, const float* __restrict__ mu_b,
                           const float* __restrict__ sig_w, const float* __restrict__ sig_b,
                           const float* __restrict__ iw, const float* __restrict__ ib,
                           float* __restrict__ h0, float* __restrict__ c0,
                           int m0, SMem& sm) {
  const int tid = threadIdx.x;
  if (tid < 16 * Z_) {
    int row = tid / Z_, qz = tid - row * Z_;
    const float* hr = h + (size_t)(m0 + row) * H_;
    float mu = mu_b[qz], sg = sig_b[qz];
    for (int k = 0; k < H_; ++k) {
      float hv = hr[k];
      mu = fmaf(hv, mu_w[k * Z_ + qz], mu);
      sg = fmaf(hv, sig_w[k * Z_ + qz], sg);
    }
    sm.zs[tid] = mu + eps[qz] * sg;
  }
  __syncthreads();
  for (int i = tid; i < 16 * H_; i += 256) {
    int row = i / H_, col = i - row * H_;
    float acc = ib[col];
#pragma unroll
    for (int qz = 0; qz < Z_; ++qz)
      acc = fmaf(sm.zs[row * Z_ + qz], iw[qz * H_ + col], acc);
    h0[(size_t)(m0 + row) * H_ + col] = acc;
    c0[(size_t)(m0 + row) * H_ + col] = acc;
  }
}

// ---------------------------------------------------------------------------
// The persistent mega-kernel: prologue (WP/EK/XK) + encoder + latent +
// autoregressive decoder, with per-row-group-domain barriers.
// ---------------------------------------------------------------------------
__global__ __launch_bounds__(256, 2) void mega(
    const int* __restrict__ inputs, const float* __restrict__ eps,
    const float* __restrict__ emb,
    const float* __restrict__ inf_k, const float* __restrict__ inf_rk,
    const float* __restrict__ inf_b,
    const float* __restrict__ mu_w, const float* __restrict__ mu_b,
    const float* __restrict__ sig_w, const float* __restrict__ sig_b,
    const float* __restrict__ init_w, const float* __restrict__ init_b,
    const float* __restrict__ gen_k, const float* __restrict__ gen_rk,
    const float* __restrict__ gen_b,
    const float* __restrict__ out_w, const float* __restrict__ out_b,
    float* __restrict__ out,
    float* __restrict__ EK, float* __restrict__ XK, float* __restrict__ WP,
    float* __restrict__ hbase, unsigned long long* __restrict__ tok,
    unsigned* __restrict__ bars, int B) {
  __shared__ SMem sm;
  const int b = blockIdx.x;
  const int tid = threadIdx.x;
  const int rg = b >> 5;          // row-group domain 0..15 (16 rows each)
  const int ct = b & 31;          // role within domain
  const int m0 = rg * 16;
  const int BH = B * H_;
  unsigned* dbar = bars + rg * 32;        // 128B per domain
  unsigned* gbar = bars + 16 * 32;        // global barrier line

  float* he[2] = {hbase,          hbase + 2 * BH};
  float* ce[2] = {hbase + BH,     hbase + 3 * BH};
  float* hd[2] = {hbase + 4 * BH, hbase + 6 * BH};
  float* cd[2] = {hbase + 5 * BH, hbase + 7 * BH};

  // ---- prologue: pad WP; EK = emb@gen_k; XK = gather(emb)@inf_k ----
  for (int i = b * 256 + tid; i < H_ * VP_; i += NB_ * 256) {
    int k = i >> 13, j = i & (VP_ - 1);
    WP[i] = (j < V_) ? out_w[(size_t)k * V_ + j] : 0.0f;
  }
  for (int s = 0; s < 3; ++s) {                 // 1536 tiles = 512*3
    int tt = b + NB_ * s;
    gemm_tile(emb, gen_k, EK, V_, tt % 3, (tt / 3) * 16, nullptr, 0, B, sm.AT_g);
  }
  for (int s = 0; s < 3; ++s) {                 // 1200 tiles
    int tt = b + NB_ * s;
    if (tt < 1200)
      gemm_tile(emb, inf_k, XK, T_ * B, tt % 3, (tt / 3) * 16, inputs, 1, B, sm.AT_g);
  }
  bar_sync(gbar, NB_);

  // ---- encoder: 25 steps, domain-local sync ----
  for (int t = 0; t < T_; ++t) {
    if (ct < 24)
      lstm_dev<0>(XK + (size_t)t * B * FH_, inf_rk, inf_b,
                  he[t & 1], ce[t & 1], he[(t + 1) & 1], ce[(t + 1) & 1],
                  nullptr, ct, m0, sm);
    bar_sync(dbar, 32);
  }

  // ---- latent ----
  if (ct == 0)
    latent_dev(he[T_ & 1], eps, mu_w, mu_b, sig_w, sig_b, init_w, init_b,
               hd[0], cd[0], m0, sm);
  bar_sync(dbar, 32);

  // ---- autoregressive decoder ----
  for (int t = 0; t < T_; ++t) {
    if (ct < 24)
      lstm_dev<1>(EK, gen_rk, gen_b,
                  hd[t & 1], cd[t & 1], hd[(t + 1) & 1], cd[(t + 1) & 1],
                  t ? (tok + (size_t)(t - 1) * B) : nullptr, ct, m0, sm);
    bar_sync(dbar, 32);
    logits_dev(hd[(t + 1) & 1], WP, out_b, out, t, tok + (size_t)t * B,
               ct, m0, sm.AT_l);
    bar_sync(dbar, 32);
  }
}

// ---------------------------------------------------------------------------
extern "C" void kernel_launch(void* const* d_in, const int* in_sizes, int n_in,
                              void* d_out, int out_size, void* d_ws, size_t ws_size,
                              hipStream_t stream) {
  const int*   inputs = (const int*)  d_in[0];
  const float* eps    = (const float*)d_in[1];
  const float* emb    = (const float*)d_in[2];
  const float* inf_k  = (const float*)d_in[3];
  const float* inf_rk = (const float*)d_in[4];
  const float* inf_b  = (const float*)d_in[5];
  const float* mu_w   = (const float*)d_in[6];
  const float* mu_b   = (const float*)d_in[7];
  const float* sig_w  = (const float*)d_in[8];
  const float* sig_b  = (const float*)d_in[9];
  const float* init_w = (const float*)d_in[10];
  const float* init_b = (const float*)d_in[11];
  const float* gen_k  = (const float*)d_in[12];
  const float* gen_rk = (const float*)d_in[13];
  const float* gen_b  = (const float*)d_in[14];
  const float* out_w  = (const float*)d_in[15];
  const float* out_b  = (const float*)d_in[16];
  float* out = (float*)d_out;

  const int B = in_sizes[0] / T_;   // 256
  const int BH = B * H_;

  float* ws = (float*)d_ws;
  size_t off = 0;
  float* hbase = ws + off;                         off += (size_t)8 * BH;
  unsigned long long* tok = (unsigned long long*)(ws + off); off += (size_t)T_ * B * 2;
  unsigned* bars = (unsigned*)(ws + off);          off += 1024;
  size_t zero_bytes = off * sizeof(float);         // states + tok + bars
  float* EK = ws + off;                            off += (size_t)V_ * FH_;
  float* XK = ws + off;                            off += (size_t)T_ * B * FH_;
  float* WP = ws + off;                            off += (size_t)H_ * VP_;

  hipMemsetAsync(ws, 0, zero_bytes, stream);

  mega<<<NB_, 256, 0, stream>>>(inputs, eps, emb, inf_k, inf_rk, inf_b,
                                mu_w, mu_b, sig_w, sig_b, init_w, init_b,
                                gen_k, gen_rk, gen_b, out_w, out_b, out,
                                EK, XK, WP, hbase, tok, bars, B);
}